// Round 10
// baseline (656.760 us; speedup 1.0000x reference)
//
#include <hip/hip_runtime.h>
#include <cmath>

// ---------------------------------------------------------------------------
// Verified bit-exact numerics (r5-r9): fp32, uncontracted, correctly-rounded
// sqrt/div/exp via fp64 helpers; ascending-k single-accumulator fmaf chains.
// ---------------------------------------------------------------------------
__device__ __forceinline__ float bn_relu32(float h, float g, float b, float m, float v) {
#pragma clang fp contract(off)
    float vp = v + 1e-5f;
    float sq = (float)sqrt((double)vp);
    float rs = (float)(1.0 / (double)sq);
    float t = ((h - m) * rs) * g + b;
    return fmaxf(t, 0.0f);
}

__device__ __forceinline__ float hard_gate(float x) {
#pragma clang fp contract(off)
    float e = (float)exp((double)(-x));
    float d = 1.0f + e;
    float sg = (float)(1.0 / (double)d);
    float s = 1.2f * sg - 0.1f;
    s = fminf(fmaxf(s, 0.0f), 1.0f);
    return (s > 0.49999f) ? 1.0f : 0.0f;
}

// ---------------------------------------------------------------------------
// Tiled fp32 GEMM + fused BN/ReLU epilogue, BK=32, register-prefetch
// double-buffer (load tile kt+1 into regs before computing kt; LDS write
// after the post-compute barrier). Thread owns TM rows x TN cols; TN=8 cols
// split as {tx*4, BN/2+tx*4} (2-way bank alias = free). Per-output: single
// accumulator, strictly ascending k -> bit-exact recipe.
// ---------------------------------------------------------------------------
template<int BM, int BN, int TM, int TN, int NT, int MINW>
__global__ __launch_bounds__(NT, MINW)
void gemm_lbr(const float* __restrict__ A, long lda,
              const float* __restrict__ W, long ldw,
              const float* __restrict__ Pg, const float* __restrict__ Pb,
              const float* __restrict__ Pm, const float* __restrict__ Pv,
              float* __restrict__ C, long ldc, int K)
{
    constexpr int BK = 32, PAD = 4;
    constexpr int LA = (BM * BK) / (4 * NT);
    constexpr int LB = (BN * BK) / (4 * NT);
    constexpr int NX = BN / TN;
    __shared__ float As[BK][BM + PAD];
    __shared__ float Bs[BK][BN + PAD];

    const int t = threadIdx.x;
    const long m0 = (long)blockIdx.y * BM;
    const int n0 = blockIdx.x * BN;
    const float* Ab = A + m0 * lda;
    const float* Wb = W + (long)n0 * ldw;
    const int tx = t % NX, ty = t / NX;

    float4 ra[LA], rb[LB];

    auto load_tile = [&](int k0) {
#pragma unroll
        for (int i = 0; i < LA; ++i) {
            int idx = t + i * NT;
            int m = idx >> 3, kq = (idx & 7) << 2;
            ra[i] = *reinterpret_cast<const float4*>(Ab + m * lda + k0 + kq);
        }
#pragma unroll
        for (int i = 0; i < LB; ++i) {
            int idx = t + i * NT;
            int n = idx >> 3, kq = (idx & 7) << 2;
            rb[i] = *reinterpret_cast<const float4*>(Wb + n * ldw + k0 + kq);
        }
    };
    auto store_tile = [&]() {
#pragma unroll
        for (int i = 0; i < LA; ++i) {
            int idx = t + i * NT;
            int m = idx >> 3, kq = (idx & 7) << 2;
            As[kq + 0][m] = ra[i].x; As[kq + 1][m] = ra[i].y;
            As[kq + 2][m] = ra[i].z; As[kq + 3][m] = ra[i].w;
        }
#pragma unroll
        for (int i = 0; i < LB; ++i) {
            int idx = t + i * NT;
            int n = idx >> 3, kq = (idx & 7) << 2;
            Bs[kq + 0][n] = rb[i].x; Bs[kq + 1][n] = rb[i].y;
            Bs[kq + 2][n] = rb[i].z; Bs[kq + 3][n] = rb[i].w;
        }
    };

    float acc[TM][TN];
#pragma unroll
    for (int i = 0; i < TM; ++i)
#pragma unroll
        for (int j = 0; j < TN; ++j) acc[i][j] = 0.0f;

    load_tile(0);
    store_tile();
    __syncthreads();

    const int ntk = K / BK;
    for (int kt = 0; kt < ntk; ++kt) {
        if (kt + 1 < ntk) load_tile((kt + 1) * BK);   // prefetch to regs
#pragma unroll 8
        for (int kk = 0; kk < BK; ++kk) {
            float a[TM], b[TN];
#pragma unroll
            for (int i = 0; i < TM; i += 4)
                *reinterpret_cast<float4*>(&a[i]) =
                    *reinterpret_cast<const float4*>(&As[kk][ty * TM + i]);
#pragma unroll
            for (int h = 0; h < TN / 4; ++h)
                *reinterpret_cast<float4*>(&b[h * 4]) =
                    *reinterpret_cast<const float4*>(&Bs[kk][h * (BN / 2) + tx * 4]);
#pragma unroll
            for (int i = 0; i < TM; ++i)
#pragma unroll
                for (int j = 0; j < TN; ++j)
                    acc[i][j] = fmaf(a[i], b[j], acc[i][j]);
        }
        if (kt + 1 < ntk) {
            __syncthreads();
            store_tile();
            __syncthreads();
        }
    }

    const long crow = m0 + ty * TM;
#pragma unroll
    for (int h = 0; h < TN / 4; ++h) {
        int nbase = n0 + h * (BN / 2) + tx * 4;
        float gg[4], bb[4], mm[4], vv[4];
#pragma unroll
        for (int j = 0; j < 4; ++j) {
            gg[j] = Pg[nbase + j]; bb[j] = Pb[nbase + j];
            mm[j] = Pm[nbase + j]; vv[j] = Pv[nbase + j];
        }
#pragma unroll
        for (int i = 0; i < TM; ++i) {
            float4 o;
            o.x = bn_relu32(acc[i][h * 4 + 0], gg[0], bb[0], mm[0], vv[0]);
            o.y = bn_relu32(acc[i][h * 4 + 1], gg[1], bb[1], mm[1], vv[1]);
            o.z = bn_relu32(acc[i][h * 4 + 2], gg[2], bb[2], mm[2], vv[2]);
            o.w = bn_relu32(acc[i][h * 4 + 3], gg[3], bb[3], mm[3], vv[3]);
            *reinterpret_cast<float4*>(C + (crow + i) * ldc + nbase) = o;
        }
    }
}

// ---------------------------------------------------------------------------
// Fused expert layers (L5+L6), unchanged from round 9 (pass-verified).
// ---------------------------------------------------------------------------
#define B5 32
__global__ __launch_bounds__(256, 4)
void expert_fused(const float* __restrict__ h4,
                  const float* __restrict__ We1, const float* __restrict__ We2,
                  const float* __restrict__ eg, const float* __restrict__ eb,
                  const float* __restrict__ em, const float* __restrict__ ev,
                  float* __restrict__ out)
{
    __shared__ float As5[64][B5 + 4];
    __shared__ float xs[256][B5 + 4];
    __shared__ float Bs[16][256 + 4];

    const int t = threadIdx.x;
    const long m0 = (long)blockIdx.x * B5;
    const int g = blockIdx.y;

#pragma unroll
    for (int it = 0; it < 2; ++it) {
        int idx4 = t + it * 256;
        int m = idx4 >> 4, sq = (idx4 & 15) << 2;
        float4 v = *reinterpret_cast<const float4*>(h4 + (m0 + m) * 512 + g * 64 + sq);
        As5[sq + 0][m] = v.x; As5[sq + 1][m] = v.y;
        As5[sq + 2][m] = v.z; As5[sq + 3][m] = v.w;
    }

    const int tx = t & 31, ty = t >> 5;
    float acc5[4][8];
#pragma unroll
    for (int i = 0; i < 4; ++i)
#pragma unroll
        for (int j = 0; j < 8; ++j) acc5[i][j] = 0.0f;

    for (int k0 = 0; k0 < 64; k0 += 16) {
        __syncthreads();
#pragma unroll
        for (int it = 0; it < 4; ++it) {
            int idx4 = t + it * 256;
            int hh = idx4 >> 2, kq = (idx4 & 3) << 2;
            float4 v = *reinterpret_cast<const float4*>(We1 + hh * 64 + k0 + kq);
            Bs[kq + 0][hh] = v.x; Bs[kq + 1][hh] = v.y;
            Bs[kq + 2][hh] = v.z; Bs[kq + 3][hh] = v.w;
        }
        __syncthreads();
#pragma unroll
        for (int kk = 0; kk < 16; ++kk) {
            float a[4];
            *reinterpret_cast<float4*>(a) =
                *reinterpret_cast<const float4*>(&As5[k0 + kk][ty * 4]);
            float b[8];
#pragma unroll
            for (int c = 0; c < 4; ++c)
                *reinterpret_cast<float2*>(&b[c * 2]) =
                    *reinterpret_cast<const float2*>(&Bs[kk][tx * 2 + c * 64]);
#pragma unroll
            for (int i = 0; i < 4; ++i)
#pragma unroll
                for (int j = 0; j < 8; ++j)
                    acc5[i][j] = fmaf(a[i], b[j], acc5[i][j]);
        }
    }
    __syncthreads();

#pragma unroll
    for (int c = 0; c < 4; ++c)
#pragma unroll
        for (int u = 0; u < 2; ++u) {
            int hh = tx * 2 + c * 64 + u;
            long p = (long)g * 256 + hh;
            float gg = eg[p], bb = eb[p], mm = em[p], vv = ev[p];
#pragma unroll
            for (int i = 0; i < 4; ++i)
                xs[hh][ty * 4 + i] = bn_relu32(acc5[i][c * 2 + u], gg, bb, mm, vv);
        }

    float acc6[4][2];
#pragma unroll
    for (int i = 0; i < 4; ++i) { acc6[i][0] = 0.0f; acc6[i][1] = 0.0f; }

    for (int k0 = 0; k0 < 256; k0 += 16) {
        __syncthreads();
        {
            int kk = t >> 2, khq = (t & 3) << 2;
            float4 v = *reinterpret_cast<const float4*>(We2 + kk * 256 + k0 + khq);
            Bs[khq + 0][kk] = v.x; Bs[khq + 1][kk] = v.y;
            Bs[khq + 2][kk] = v.z; Bs[khq + 3][kk] = v.w;
        }
        __syncthreads();
#pragma unroll
        for (int kh = 0; kh < 16; ++kh) {
            float a[4];
            *reinterpret_cast<float4*>(a) =
                *reinterpret_cast<const float4*>(&xs[k0 + kh][ty * 4]);
            float2 b = *reinterpret_cast<const float2*>(&Bs[kh][tx * 2]);
#pragma unroll
            for (int i = 0; i < 4; ++i) {
                acc6[i][0] = fmaf(a[i], b.x, acc6[i][0]);
                acc6[i][1] = fmaf(a[i], b.y, acc6[i][1]);
            }
        }
    }

#pragma unroll
    for (int i = 0; i < 4; ++i) {
        float2 o;
        o.x = hard_gate(acc6[i][0]);
        o.y = hard_gate(acc6[i][1]);
        *reinterpret_cast<float2*>(out + (m0 + ty * 4 + i) * 512 + g * 64 + tx * 2) = o;
    }
}

// ---------------------------------------------------------------------------
// Fallback (round-7 fused kernel, pass-verified): used only if ws too small.
// ---------------------------------------------------------------------------
#define FNT 512
template<int CPT, int RPT, int EPI>
__device__ __forceinline__ void flayer(
    const float* __restrict__ I, int ldI, int K,
    const float* __restrict__ Wt, long ldW,
    const float* __restrict__ Pg, const float* __restrict__ Pb,
    const float* __restrict__ Pm, const float* __restrict__ Pv,
    float* __restrict__ O, int ldO, int n, int r0, int rstep)
{
    float acc[CPT][RPT];
#pragma unroll
    for (int c = 0; c < CPT; ++c)
#pragma unroll
        for (int r = 0; r < RPT; ++r) acc[c][r] = 0.0f;
#pragma unroll 2
    for (int k = 0; k < K; k += 4) {
        float4 av[RPT];
#pragma unroll
        for (int r = 0; r < RPT; ++r)
            av[r] = *reinterpret_cast<const float4*>(I + (r0 + r * rstep) * ldI + k);
#pragma unroll
        for (int c = 0; c < CPT; ++c) {
            float4 w = *reinterpret_cast<const float4*>(Wt + (long)(n + c * FNT) * ldW + k);
#pragma unroll
            for (int r = 0; r < RPT; ++r) {
                acc[c][r] = fmaf(av[r].x, w.x, acc[c][r]);
                acc[c][r] = fmaf(av[r].y, w.y, acc[c][r]);
                acc[c][r] = fmaf(av[r].z, w.z, acc[c][r]);
                acc[c][r] = fmaf(av[r].w, w.w, acc[c][r]);
            }
        }
    }
#pragma unroll
    for (int c = 0; c < CPT; ++c) {
        int nn = n + c * FNT;
        if constexpr (EPI == 1) {
            float gg = Pg[nn], bb = Pb[nn], mm = Pm[nn], vv = Pv[nn];
#pragma unroll
            for (int r = 0; r < RPT; ++r)
                O[(r0 + r * rstep) * ldO + nn] = bn_relu32(acc[c][r], gg, bb, mm, vv);
        } else {
#pragma unroll
            for (int r = 0; r < RPT; ++r)
                O[(r0 + r * rstep) * ldO + nn] = hard_gate(acc[c][r]);
        }
    }
}

__global__ __launch_bounds__(FNT, 4)
void tg32_fused(const float* __restrict__ prompt,
    const float* __restrict__ W1, const float* __restrict__ g1, const float* __restrict__ b1, const float* __restrict__ m1, const float* __restrict__ v1,
    const float* __restrict__ W2, const float* __restrict__ g2, const float* __restrict__ b2, const float* __restrict__ m2, const float* __restrict__ v2,
    const float* __restrict__ W3, const float* __restrict__ g3, const float* __restrict__ b3, const float* __restrict__ m3, const float* __restrict__ v3,
    const float* __restrict__ W4, const float* __restrict__ g4, const float* __restrict__ b4, const float* __restrict__ m4, const float* __restrict__ v4,
    const float* __restrict__ We1, const float* __restrict__ We2,
    const float* __restrict__ eg, const float* __restrict__ eb, const float* __restrict__ em, const float* __restrict__ ev,
    float* __restrict__ out)
{
    __shared__ __align__(16) float arena[12288];
    float* A0 = arena;
    float* A1 = arena + 4096;
    const int t = threadIdx.x;
    const long row0 = (long)blockIdx.x * 8;
    for (int i = t; i < 1024; i += FNT) {
        int r = i >> 7, c4 = (i & 127) << 2;
        *reinterpret_cast<float4*>(A0 + r * 512 + c4) =
            *reinterpret_cast<const float4*>(prompt + (row0 + r) * 512 + c4);
    }
    __syncthreads();
    flayer<1, 1, 1>(A0, 512, 512, W1, 512, g1, b1, m1, v1, A1, 64, t & 63, t >> 6, 1);
    __syncthreads();
    flayer<1, 8, 1>(A1, 64, 64, W2, 64, g2, b2, m2, v2, A0, 512, t, 0, 1);
    __syncthreads();
    flayer<2, 8, 1>(A0, 512, 512, W3, 512, g3, b3, m3, v3, A1, 1024, t, 0, 1);
    __syncthreads();
    flayer<1, 8, 1>(A1, 1024, 1024, W4, 1024, g4, b4, m4, v4, A0, 512, t, 0, 1);
    __syncthreads();
    for (int g = 0; g < 8; ++g) {
        flayer<1, 4, 1>(A0 + g * 64, 512, 64, We1, 64,
                        eg + g * 256, eb + g * 256, em + g * 256, ev + g * 256,
                        A1, 256, t & 255, (t >> 8) * 4, 1);
        __syncthreads();
        flayer<1, 1, 2>(A1, 256, 256, We2, 256, nullptr, nullptr, nullptr, nullptr,
                        out + row0 * 512 + g * 64, 512, t & 63, t >> 6, 1);
        __syncthreads();
    }
}

extern "C" void kernel_launch(void* const* d_in, const int* in_sizes, int n_in,
                              void* d_out, int out_size, void* d_ws, size_t ws_size,
                              hipStream_t stream) {
    (void)n_in; (void)out_size;
    const float* prompt = (const float*)d_in[0];
    const float* W1 = (const float*)d_in[1];
    const float* g1 = (const float*)d_in[2];
    const float* b1 = (const float*)d_in[3];
    const float* m1 = (const float*)d_in[4];
    const float* v1 = (const float*)d_in[5];
    const float* W2 = (const float*)d_in[6];
    const float* g2 = (const float*)d_in[7];
    const float* b2 = (const float*)d_in[8];
    const float* m2 = (const float*)d_in[9];
    const float* v2 = (const float*)d_in[10];
    const float* W3 = (const float*)d_in[11];
    const float* g3 = (const float*)d_in[12];
    const float* b3 = (const float*)d_in[13];
    const float* m3 = (const float*)d_in[14];
    const float* v3 = (const float*)d_in[15];
    const float* W4 = (const float*)d_in[16];
    const float* g4 = (const float*)d_in[17];
    const float* b4 = (const float*)d_in[18];
    const float* m4 = (const float*)d_in[19];
    const float* v4 = (const float*)d_in[20];
    const float* We1 = (const float*)d_in[21];
    const float* We2 = (const float*)d_in[22];
    const float* eg = (const float*)d_in[23];
    const float* eb = (const float*)d_in[24];
    const float* em = (const float*)d_in[25];
    const float* ev = (const float*)d_in[26];
    float* out = (float*)d_out;

    const long Btot = in_sizes[0] / 512;          // 16384
    const long perRow = 2112;                      // h1+h2+h3+h4 floats
    long Bc = (long)(ws_size / (perRow * 4));
    if (Bc > Btot) Bc = Btot;
    Bc &= ~127L;

    if (Bc < 128) {
        tg32_fused<<<dim3(Btot / 8), dim3(FNT), 0, stream>>>(prompt,
            W1, g1, b1, m1, v1, W2, g2, b2, m2, v2,
            W3, g3, b3, m3, v3, W4, g4, b4, m4, v4,
            We1, We2, eg, eb, em, ev, out);
        return;
    }

    float* h1 = (float*)d_ws;                      // [Bc,64]
    float* h2 = h1 + Bc * 64;                      // [Bc,512]
    float* h3 = h2 + Bc * 512;                     // [Bc,1024]
    float* h4 = h3 + Bc * 1024;                    // [Bc,512]

    for (long b0 = 0; b0 < Btot; b0 += Bc) {
        long mc = Btot - b0; if (mc > Bc) mc = Bc;
        const float* P = prompt + b0 * 512;
        // L1: [mc,512] -> [mc,64]        (Y-small)
        gemm_lbr<64, 64, 4, 4, 256, 3><<<dim3(1, mc / 64), dim3(256), 0, stream>>>(
            P, 512, W1, 512, g1, b1, m1, v1, h1, 64, 512);
        // L2: [mc,64] -> [mc,512]        (Y)
        gemm_lbr<128, 128, 8, 8, 256, 3><<<dim3(4, mc / 128), dim3(256), 0, stream>>>(
            h1, 64, W2, 64, g2, b2, m2, v2, h2, 512, 64);
        // L3: [mc,512] -> [mc,1024]      (X: TM=16, 128 thr)  -- A/B vs L4
        gemm_lbr<128, 128, 16, 8, 128, 2><<<dim3(8, mc / 128), dim3(128), 0, stream>>>(
            h2, 512, W3, 512, g3, b3, m3, v3, h3, 1024, 512);
        // L4: [mc,1024] -> [mc,512]      (Y: TM=8, 256 thr)
        gemm_lbr<128, 128, 8, 8, 256, 3><<<dim3(4, mc / 128), dim3(256), 0, stream>>>(
            h3, 1024, W4, 1024, g4, b4, m4, v4, h4, 512, 1024);
        // L5+L6 fused
        expert_fused<<<dim3(mc / 32, 8), dim3(256), 0, stream>>>(
            h4, We1, We2, eg, eb, em, ev, out + b0 * 512);
    }
}

// Round 11
// 612.243 us; speedup vs baseline: 1.0727x; 1.0727x over previous
//
#include <hip/hip_runtime.h>
#include <cmath>

// ---------------------------------------------------------------------------
// Verified bit-exact numerics (r5-r10): fp32, uncontracted, correctly-rounded
// sqrt/div/exp via fp64 helpers; ascending-k single-accumulator fmaf chains.
// ---------------------------------------------------------------------------
__device__ __forceinline__ float bn_relu32(float h, float g, float b, float m, float v) {
#pragma clang fp contract(off)
    float vp = v + 1e-5f;
    float sq = (float)sqrt((double)vp);
    float rs = (float)(1.0 / (double)sq);
    float t = ((h - m) * rs) * g + b;
    return fmaxf(t, 0.0f);
}

__device__ __forceinline__ float hard_gate(float x) {
#pragma clang fp contract(off)
    float e = (float)exp((double)(-x));
    float d = 1.0f + e;
    float sg = (float)(1.0 / (double)d);
    float s = 1.2f * sg - 0.1f;
    s = fminf(fmaxf(s, 0.0f), 1.0f);
    return (s > 0.49999f) ? 1.0f : 0.0f;
}

// ---------------------------------------------------------------------------
// Tiled fp32 GEMM + fused BN/ReLU epilogue (round-9 template, BK=16).
// Thread owns TM rows x TN cols; TN cols are TN/4 float4 groups at stride
// 4*NX floats (16 distinct float4 in 256B window = 2-way alias, free).
// Per-output: single accumulator, strictly ascending k -> bit-exact recipe.
// ---------------------------------------------------------------------------
template<int BM, int BN, int TM, int TN, int NT, int MINW>
__global__ __launch_bounds__(NT, MINW)
void gemm_lbr(const float* __restrict__ A, long lda,
              const float* __restrict__ W, long ldw,
              const float* __restrict__ Pg, const float* __restrict__ Pb,
              const float* __restrict__ Pm, const float* __restrict__ Pv,
              float* __restrict__ C, long ldc, int K)
{
    constexpr int BK = 16, PAD = 4;
    constexpr int NX = BN / TN;           // threads along n
    constexpr int NG = TN / 4;            // float4 col-groups per thread
    constexpr int CS = 4 * NX;            // col-group stride in floats
    __shared__ float As[BK][BM + PAD];
    __shared__ float Bs[BK][BN + PAD];

    const int t = threadIdx.x;
    const long m0 = (long)blockIdx.y * BM;
    const int n0 = blockIdx.x * BN;
    const float* Ab = A + m0 * lda;
    const float* Wb = W + (long)n0 * ldw;

    const int tx = t % NX;
    const int ty = t / NX;

    float acc[TM][TN];
#pragma unroll
    for (int i = 0; i < TM; ++i)
#pragma unroll
        for (int j = 0; j < TN; ++j) acc[i][j] = 0.0f;

    for (int k0 = 0; k0 < K; k0 += BK) {
#pragma unroll
        for (int i = 0; i < (BM * BK) / (4 * NT); ++i) {
            int idx = t + i * NT;
            int m = idx >> 2, kq = (idx & 3) << 2;
            float4 v = *reinterpret_cast<const float4*>(Ab + m * lda + k0 + kq);
            As[kq + 0][m] = v.x; As[kq + 1][m] = v.y;
            As[kq + 2][m] = v.z; As[kq + 3][m] = v.w;
        }
#pragma unroll
        for (int i = 0; i < (BN * BK) / (4 * NT); ++i) {
            int idx = t + i * NT;
            int n = idx >> 2, kq = (idx & 3) << 2;
            float4 v = *reinterpret_cast<const float4*>(Wb + n * ldw + k0 + kq);
            Bs[kq + 0][n] = v.x; Bs[kq + 1][n] = v.y;
            Bs[kq + 2][n] = v.z; Bs[kq + 3][n] = v.w;
        }
        __syncthreads();

#pragma unroll
        for (int kk = 0; kk < BK; ++kk) {
            float a[TM], b[TN];
#pragma unroll
            for (int i = 0; i < TM; i += 4)
                *reinterpret_cast<float4*>(&a[i]) =
                    *reinterpret_cast<const float4*>(&As[kk][ty * TM + i]);
#pragma unroll
            for (int h = 0; h < NG; ++h)
                *reinterpret_cast<float4*>(&b[h * 4]) =
                    *reinterpret_cast<const float4*>(&Bs[kk][h * CS + tx * 4]);
#pragma unroll
            for (int i = 0; i < TM; ++i)
#pragma unroll
                for (int j = 0; j < TN; ++j)
                    acc[i][j] = fmaf(a[i], b[j], acc[i][j]);
        }
        __syncthreads();
    }

    const long crow = m0 + ty * TM;
#pragma unroll
    for (int h = 0; h < NG; ++h) {
        int nbase = n0 + h * CS + tx * 4;
        float gg[4], bb[4], mm[4], vv[4];
#pragma unroll
        for (int j = 0; j < 4; ++j) {
            gg[j] = Pg[nbase + j]; bb[j] = Pb[nbase + j];
            mm[j] = Pm[nbase + j]; vv[j] = Pv[nbase + j];
        }
#pragma unroll
        for (int i = 0; i < TM; ++i) {
            float4 o;
            o.x = bn_relu32(acc[i][h * 4 + 0], gg[0], bb[0], mm[0], vv[0]);
            o.y = bn_relu32(acc[i][h * 4 + 1], gg[1], bb[1], mm[1], vv[1]);
            o.z = bn_relu32(acc[i][h * 4 + 2], gg[2], bb[2], mm[2], vv[2]);
            o.w = bn_relu32(acc[i][h * 4 + 3], gg[3], bb[3], mm[3], vv[3]);
            *reinterpret_cast<float4*>(C + (crow + i) * ldc + nbase) = o;
        }
    }
}

// ---------------------------------------------------------------------------
// Fused expert layers (L5+L6), unchanged (pass-verified r9/r10).
// ---------------------------------------------------------------------------
#define B5 32
__global__ __launch_bounds__(256, 4)
void expert_fused(const float* __restrict__ h4,
                  const float* __restrict__ We1, const float* __restrict__ We2,
                  const float* __restrict__ eg, const float* __restrict__ eb,
                  const float* __restrict__ em, const float* __restrict__ ev,
                  float* __restrict__ out)
{
    __shared__ float As5[64][B5 + 4];
    __shared__ float xs[256][B5 + 4];
    __shared__ float Bs[16][256 + 4];

    const int t = threadIdx.x;
    const long m0 = (long)blockIdx.x * B5;
    const int g = blockIdx.y;

#pragma unroll
    for (int it = 0; it < 2; ++it) {
        int idx4 = t + it * 256;
        int m = idx4 >> 4, sq = (idx4 & 15) << 2;
        float4 v = *reinterpret_cast<const float4*>(h4 + (m0 + m) * 512 + g * 64 + sq);
        As5[sq + 0][m] = v.x; As5[sq + 1][m] = v.y;
        As5[sq + 2][m] = v.z; As5[sq + 3][m] = v.w;
    }

    const int tx = t & 31, ty = t >> 5;
    float acc5[4][8];
#pragma unroll
    for (int i = 0; i < 4; ++i)
#pragma unroll
        for (int j = 0; j < 8; ++j) acc5[i][j] = 0.0f;

    for (int k0 = 0; k0 < 64; k0 += 16) {
        __syncthreads();
#pragma unroll
        for (int it = 0; it < 4; ++it) {
            int idx4 = t + it * 256;
            int hh = idx4 >> 2, kq = (idx4 & 3) << 2;
            float4 v = *reinterpret_cast<const float4*>(We1 + hh * 64 + k0 + kq);
            Bs[kq + 0][hh] = v.x; Bs[kq + 1][hh] = v.y;
            Bs[kq + 2][hh] = v.z; Bs[kq + 3][hh] = v.w;
        }
        __syncthreads();
#pragma unroll
        for (int kk = 0; kk < 16; ++kk) {
            float a[4];
            *reinterpret_cast<float4*>(a) =
                *reinterpret_cast<const float4*>(&As5[k0 + kk][ty * 4]);
            float b[8];
#pragma unroll
            for (int c = 0; c < 4; ++c)
                *reinterpret_cast<float2*>(&b[c * 2]) =
                    *reinterpret_cast<const float2*>(&Bs[kk][tx * 2 + c * 64]);
#pragma unroll
            for (int i = 0; i < 4; ++i)
#pragma unroll
                for (int j = 0; j < 8; ++j)
                    acc5[i][j] = fmaf(a[i], b[j], acc5[i][j]);
        }
    }
    __syncthreads();

#pragma unroll
    for (int c = 0; c < 4; ++c)
#pragma unroll
        for (int u = 0; u < 2; ++u) {
            int hh = tx * 2 + c * 64 + u;
            long p = (long)g * 256 + hh;
            float gg = eg[p], bb = eb[p], mm = em[p], vv = ev[p];
#pragma unroll
            for (int i = 0; i < 4; ++i)
                xs[hh][ty * 4 + i] = bn_relu32(acc5[i][c * 2 + u], gg, bb, mm, vv);
        }

    float acc6[4][2];
#pragma unroll
    for (int i = 0; i < 4; ++i) { acc6[i][0] = 0.0f; acc6[i][1] = 0.0f; }

    for (int k0 = 0; k0 < 256; k0 += 16) {
        __syncthreads();
        {
            int kk = t >> 2, khq = (t & 3) << 2;
            float4 v = *reinterpret_cast<const float4*>(We2 + kk * 256 + k0 + khq);
            Bs[khq + 0][kk] = v.x; Bs[khq + 1][kk] = v.y;
            Bs[khq + 2][kk] = v.z; Bs[khq + 3][kk] = v.w;
        }
        __syncthreads();
#pragma unroll
        for (int kh = 0; kh < 16; ++kh) {
            float a[4];
            *reinterpret_cast<float4*>(a) =
                *reinterpret_cast<const float4*>(&xs[k0 + kh][ty * 4]);
            float2 b = *reinterpret_cast<const float2*>(&Bs[kh][tx * 2]);
#pragma unroll
            for (int i = 0; i < 4; ++i) {
                acc6[i][0] = fmaf(a[i], b.x, acc6[i][0]);
                acc6[i][1] = fmaf(a[i], b.y, acc6[i][1]);
            }
        }
    }

#pragma unroll
    for (int i = 0; i < 4; ++i) {
        float2 o;
        o.x = hard_gate(acc6[i][0]);
        o.y = hard_gate(acc6[i][1]);
        *reinterpret_cast<float2*>(out + (m0 + ty * 4 + i) * 512 + g * 64 + tx * 2) = o;
    }
}

// ---------------------------------------------------------------------------
// Fallback (round-7 fused kernel, pass-verified): used only if ws too small.
// ---------------------------------------------------------------------------
#define FNT 512
template<int CPT, int RPT, int EPI>
__device__ __forceinline__ void flayer(
    const float* __restrict__ I, int ldI, int K,
    const float* __restrict__ Wt, long ldW,
    const float* __restrict__ Pg, const float* __restrict__ Pb,
    const float* __restrict__ Pm, const float* __restrict__ Pv,
    float* __restrict__ O, int ldO, int n, int r0, int rstep)
{
    float acc[CPT][RPT];
#pragma unroll
    for (int c = 0; c < CPT; ++c)
#pragma unroll
        for (int r = 0; r < RPT; ++r) acc[c][r] = 0.0f;
#pragma unroll 2
    for (int k = 0; k < K; k += 4) {
        float4 av[RPT];
#pragma unroll
        for (int r = 0; r < RPT; ++r)
            av[r] = *reinterpret_cast<const float4*>(I + (r0 + r * rstep) * ldI + k);
#pragma unroll
        for (int c = 0; c < CPT; ++c) {
            float4 w = *reinterpret_cast<const float4*>(Wt + (long)(n + c * FNT) * ldW + k);
#pragma unroll
            for (int r = 0; r < RPT; ++r) {
                acc[c][r] = fmaf(av[r].x, w.x, acc[c][r]);
                acc[c][r] = fmaf(av[r].y, w.y, acc[c][r]);
                acc[c][r] = fmaf(av[r].z, w.z, acc[c][r]);
                acc[c][r] = fmaf(av[r].w, w.w, acc[c][r]);
            }
        }
    }
#pragma unroll
    for (int c = 0; c < CPT; ++c) {
        int nn = n + c * FNT;
        if constexpr (EPI == 1) {
            float gg = Pg[nn], bb = Pb[nn], mm = Pm[nn], vv = Pv[nn];
#pragma unroll
            for (int r = 0; r < RPT; ++r)
                O[(r0 + r * rstep) * ldO + nn] = bn_relu32(acc[c][r], gg, bb, mm, vv);
        } else {
#pragma unroll
            for (int r = 0; r < RPT; ++r)
                O[(r0 + r * rstep) * ldO + nn] = hard_gate(acc[c][r]);
        }
    }
}

__global__ __launch_bounds__(FNT, 4)
void tg32_fused(const float* __restrict__ prompt,
    const float* __restrict__ W1, const float* __restrict__ g1, const float* __restrict__ b1, const float* __restrict__ m1, const float* __restrict__ v1,
    const float* __restrict__ W2, const float* __restrict__ g2, const float* __restrict__ b2, const float* __restrict__ m2, const float* __restrict__ v2,
    const float* __restrict__ W3, const float* __restrict__ g3, const float* __restrict__ b3, const float* __restrict__ m3, const float* __restrict__ v3,
    const float* __restrict__ W4, const float* __restrict__ g4, const float* __restrict__ b4, const float* __restrict__ m4, const float* __restrict__ v4,
    const float* __restrict__ We1, const float* __restrict__ We2,
    const float* __restrict__ eg, const float* __restrict__ eb, const float* __restrict__ em, const float* __restrict__ ev,
    float* __restrict__ out)
{
    __shared__ __align__(16) float arena[12288];
    float* A0 = arena;
    float* A1 = arena + 4096;
    const int t = threadIdx.x;
    const long row0 = (long)blockIdx.x * 8;
    for (int i = t; i < 1024; i += FNT) {
        int r = i >> 7, c4 = (i & 127) << 2;
        *reinterpret_cast<float4*>(A0 + r * 512 + c4) =
            *reinterpret_cast<const float4*>(prompt + (row0 + r) * 512 + c4);
    }
    __syncthreads();
    flayer<1, 1, 1>(A0, 512, 512, W1, 512, g1, b1, m1, v1, A1, 64, t & 63, t >> 6, 1);
    __syncthreads();
    flayer<1, 8, 1>(A1, 64, 64, W2, 64, g2, b2, m2, v2, A0, 512, t, 0, 1);
    __syncthreads();
    flayer<2, 8, 1>(A0, 512, 512, W3, 512, g3, b3, m3, v3, A1, 1024, t, 0, 1);
    __syncthreads();
    flayer<1, 8, 1>(A1, 1024, 1024, W4, 1024, g4, b4, m4, v4, A0, 512, t, 0, 1);
    __syncthreads();
    for (int g = 0; g < 8; ++g) {
        flayer<1, 4, 1>(A0 + g * 64, 512, 64, We1, 64,
                        eg + g * 256, eb + g * 256, em + g * 256, ev + g * 256,
                        A1, 256, t & 255, (t >> 8) * 4, 1);
        __syncthreads();
        flayer<1, 1, 2>(A1, 256, 256, We2, 256, nullptr, nullptr, nullptr, nullptr,
                        out + row0 * 512 + g * 64, 512, t & 63, t >> 6, 1);
        __syncthreads();
    }
}

extern "C" void kernel_launch(void* const* d_in, const int* in_sizes, int n_in,
                              void* d_out, int out_size, void* d_ws, size_t ws_size,
                              hipStream_t stream) {
    (void)n_in; (void)out_size;
    const float* prompt = (const float*)d_in[0];
    const float* W1 = (const float*)d_in[1];
    const float* g1 = (const float*)d_in[2];
    const float* b1 = (const float*)d_in[3];
    const float* m1 = (const float*)d_in[4];
    const float* v1 = (const float*)d_in[5];
    const float* W2 = (const float*)d_in[6];
    const float* g2 = (const float*)d_in[7];
    const float* b2 = (const float*)d_in[8];
    const float* m2 = (const float*)d_in[9];
    const float* v2 = (const float*)d_in[10];
    const float* W3 = (const float*)d_in[11];
    const float* g3 = (const float*)d_in[12];
    const float* b3 = (const float*)d_in[13];
    const float* m3 = (const float*)d_in[14];
    const float* v3 = (const float*)d_in[15];
    const float* W4 = (const float*)d_in[16];
    const float* g4 = (const float*)d_in[17];
    const float* b4 = (const float*)d_in[18];
    const float* m4 = (const float*)d_in[19];
    const float* v4 = (const float*)d_in[20];
    const float* We1 = (const float*)d_in[21];
    const float* We2 = (const float*)d_in[22];
    const float* eg = (const float*)d_in[23];
    const float* eb = (const float*)d_in[24];
    const float* em = (const float*)d_in[25];
    const float* ev = (const float*)d_in[26];
    float* out = (float*)d_out;

    const long Btot = in_sizes[0] / 512;          // 16384
    const long perRow = 2112;                      // h1+h2+h3+h4 floats
    long Bc = (long)(ws_size / (perRow * 4));
    if (Bc > Btot) Bc = Btot;
    Bc &= ~127L;

    if (Bc < 128) {
        tg32_fused<<<dim3(Btot / 8), dim3(FNT), 0, stream>>>(prompt,
            W1, g1, b1, m1, v1, W2, g2, b2, m2, v2,
            W3, g3, b3, m3, v3, W4, g4, b4, m4, v4,
            We1, We2, eg, eb, em, ev, out);
        return;
    }

    float* h1 = (float*)d_ws;                      // [Bc,64]
    float* h2 = h1 + Bc * 64;                      // [Bc,512]
    float* h3 = h2 + Bc * 512;                     // [Bc,1024]
    float* h4 = h3 + Bc * 1024;                    // [Bc,512]

    for (long b0 = 0; b0 < Btot; b0 += Bc) {
        long mc = Btot - b0; if (mc > Bc) mc = Bc;
        const float* P = prompt + b0 * 512;
        // L1: [mc,512] -> [mc,64]        (r9 template)
        gemm_lbr<64, 64, 4, 4, 256, 3><<<dim3(1, mc / 64), dim3(256), 0, stream>>>(
            P, 512, W1, 512, g1, b1, m1, v1, h1, 64, 512);
        // L2: [mc,64] -> [mc,512]        (r9 template)
        gemm_lbr<128, 128, 8, 8, 256, 3><<<dim3(4, mc / 128), dim3(256), 0, stream>>>(
            h1, 64, W2, 64, g2, b2, m2, v2, h2, 512, 64);
        // L3: [mc,512] -> [mc,1024]      A/B EXPERIMENT: TN=16 (fewer LDS insts/FLOP)
        gemm_lbr<128, 256, 8, 16, 256, 2><<<dim3(4, mc / 128), dim3(256), 0, stream>>>(
            h2, 512, W3, 512, g3, b3, m3, v3, h3, 1024, 512);
        // L4: [mc,1024] -> [mc,512]      (r9 template, control)
        gemm_lbr<128, 128, 8, 8, 256, 3><<<dim3(4, mc / 128), dim3(256), 0, stream>>>(
            h3, 1024, W4, 1024, g4, b4, m4, v4, h4, 512, 1024);
        // L5+L6 fused
        expert_fused<<<dim3(mc / 32, 8), dim3(256), 0, stream>>>(
            h4, We1, We2, eg, eb, em, ev, out + b0 * 512);
    }
}